// Round 2
// baseline (317.873 us; speedup 1.0000x reference)
//
#include <hip/hip_runtime.h>

// Gathered skinny GEMM: out[b, r] = sum_d x[b,d] * w[indices[r], d]
//   x: [32][4096] f32, w: [11008][4096] f32, indices: [4403] i32,
//   out: [32][4403] f32 (einsum 'bsd,rd->bsr', s==1)
//
// R2: two-phase split-K, NO atomics (R1's 9.4M contended device-scope
// atomicAdds were the prime suspect for the 294us result).
//   Phase 1: thread-per-gathered-row, KSPLIT=32 K-chunks, partials stored
//            flat to d_ws (coalesced plain stores).
//   Phase 2: sum the 32 partials per output, write d_out (no memset needed).
// Floors: VALU 7.3us (fp32 FMA, no fp32 MFMA on CDNA4), HBM ~11.4us
// (72 MB gathered weight @ 6.3 TB/s).

#define D_MODEL   4096
#define REMAINED  4403
#define BATCH     32
#define BLOCK     256
#define RTILES    ((REMAINED + BLOCK - 1) / BLOCK)   // 18
#define RSLOTS    (RTILES * BLOCK)                   // 4608 (padded rows)
#define KSPLIT    32
#define KCHUNK    (D_MODEL / KSPLIT)                 // 128 floats per block
#define K4CHUNK   (KCHUNK / 4)                       // 32 float4 per block
#define GRID1     (RTILES * KSPLIT)                  // 576 blocks

// ws layout: partial[ks][b][rslot]  -> ((ks*BATCH + b)*RSLOTS + rslot)
// size = 32*32*4608*4 B = 18.9 MB (ws_size is ~688 MB, plenty)

__global__ __launch_bounds__(BLOCK) void gather_gemv_p1(
    const float* __restrict__ x,
    const float* __restrict__ w,
    const int*   __restrict__ idx,
    float*       __restrict__ partial)
{
    const int rt = blockIdx.x % RTILES;
    const int ks = blockIdx.x / RTILES;

    const int  r      = rt * BLOCK + (int)threadIdx.x;
    const bool active = (r < REMAINED);
    const int  rc     = active ? r : (REMAINED - 1);
    const int  row    = idx[rc];

    const float4* __restrict__ wrow = (const float4*)(w + (size_t)row * D_MODEL);
    const float4* __restrict__ x4   = (const float4*)x;

    const int k4_0 = ks * K4CHUNK;

    float acc[BATCH];
#pragma unroll
    for (int b = 0; b < BATCH; ++b) acc[b] = 0.f;

    // 8 outer iterations; each loads 4 float4 = 64 B/lane (a full cacheline,
    // so the row-divergent gather still consumes every fetched byte).
    for (int kb = 0; kb < K4CHUNK / 4; ++kb) {
        float4 wv[4];
#pragma unroll
        for (int u = 0; u < 4; ++u) wv[u] = wrow[k4_0 + kb * 4 + u];

#pragma unroll
        for (int u = 0; u < 4; ++u) {
            const int k4 = k4_0 + kb * 4 + u;
#pragma unroll
            for (int b = 0; b < BATCH; ++b) {
                // offset is wave-uniform -> scalar-cache load + broadcast
                const float4 xv = x4[b * (D_MODEL / 4) + k4];
                acc[b] = fmaf(wv[u].x, xv.x, acc[b]);
                acc[b] = fmaf(wv[u].y, xv.y, acc[b]);
                acc[b] = fmaf(wv[u].z, xv.z, acc[b]);
                acc[b] = fmaf(wv[u].w, xv.w, acc[b]);
            }
        }
    }

    // Plain coalesced stores of the partial tile; padded rows store 0 so
    // phase 2 needs no bounds logic on reads.
    float* p = partial + (size_t)ks * BATCH * RSLOTS + r;
    if (!active) {
#pragma unroll
        for (int b = 0; b < BATCH; ++b) acc[b] = 0.f;
    }
#pragma unroll
    for (int b = 0; b < BATCH; ++b)
        p[(size_t)b * RSLOTS] = acc[b];
}

// Phase 2: out[b][r] = sum_ks partial[ks][b][r]
// One thread per 4 consecutive rslots of one batch row.
#define GRID2  ((BATCH * (RSLOTS / 4)) / BLOCK)      // 32*1152/256 = 144

__global__ __launch_bounds__(BLOCK) void gather_gemv_p2(
    const float* __restrict__ partial,
    float*       __restrict__ out)
{
    const int g  = blockIdx.x * BLOCK + threadIdx.x;   // 0 .. 36863
    const int b  = g / (RSLOTS / 4);
    const int r4 = g % (RSLOTS / 4);

    const float4* p = (const float4*)(partial) + ((size_t)b * (RSLOTS / 4) + r4);

    float4 s = make_float4(0.f, 0.f, 0.f, 0.f);
#pragma unroll
    for (int ks = 0; ks < KSPLIT; ++ks) {
        // stride between ks planes: BATCH*RSLOTS floats = BATCH*RSLOTS/4 float4
        const float4 v = p[(size_t)ks * BATCH * (RSLOTS / 4)];
        s.x += v.x; s.y += v.y; s.z += v.z; s.w += v.w;
    }

    const int r0 = r4 * 4;
    float* o = out + (size_t)b * REMAINED;
    if (r0 + 3 < REMAINED) {
        o[r0 + 0] = s.x; o[r0 + 1] = s.y; o[r0 + 2] = s.z; o[r0 + 3] = s.w;
    } else {
        if (r0 + 0 < REMAINED) o[r0 + 0] = s.x;
        if (r0 + 1 < REMAINED) o[r0 + 1] = s.y;
        if (r0 + 2 < REMAINED) o[r0 + 2] = s.z;
        if (r0 + 3 < REMAINED) o[r0 + 3] = s.w;
    }
}

extern "C" void kernel_launch(void* const* d_in, const int* in_sizes, int n_in,
                              void* d_out, int out_size, void* d_ws, size_t ws_size,
                              hipStream_t stream) {
    const float* x   = (const float*)d_in[0];
    const float* w   = (const float*)d_in[1];
    const int*   idx = (const int*)d_in[2];
    float*       out = (float*)d_out;
    float*       ws  = (float*)d_ws;

    gather_gemv_p1<<<GRID1, BLOCK, 0, stream>>>(x, w, idx, ws);
    gather_gemv_p2<<<GRID2, BLOCK, 0, stream>>>(ws, out);
}

// Round 3
// 256.631 us; speedup vs baseline: 1.2386x; 1.2386x over previous
//
#include <hip/hip_runtime.h>

// Gathered skinny GEMM: out[b, r] = sum_d x[b,d] * w[indices[r], d]
//   x: [32][4096] f32, w: [11008][4096] f32, indices: [4403] i32,
//   out: [32][4403] f32
//
// R3: R2's phase-1 was latency-bound (VALUBusy 29%, hbm 6%, VGPR=36):
// compiler serialized the 32 uniform x-VMEM loads per k-group into a
// load->wait->4xFMA chain. Fix:
//   (a) stage x-chunk (32 b x 128 k = 16 KB) in LDS once per block; inner
//       loop reads x via broadcast ds_read_b128 (same addr all lanes,
//       conflict-free, lgkm pipe - overlaps VALU).
//   (b) software-pipeline the w stream: prefetch next 64 B/lane line while
//       FMA-ing current one, so HBM latency hides behind the 1024-cycle
//       FMA block per k-group.
// VALU floor: 2304 waves * 8192 cyc / 1024 SIMD = 7.7 us for phase 1.

#define D_MODEL   4096
#define REMAINED  4403
#define BATCH     32
#define BLOCK     256
#define RTILES    ((REMAINED + BLOCK - 1) / BLOCK)   // 18
#define RSLOTS    (RTILES * BLOCK)                   // 4608
#define KSPLIT    32
#define KCHUNK    (D_MODEL / KSPLIT)                 // 128 floats
#define K4CHUNK   (KCHUNK / 4)                       // 32 float4
#define GRID1     (RTILES * KSPLIT)                  // 576 blocks

__global__ __launch_bounds__(BLOCK) void gather_gemv_p1(
    const float* __restrict__ x,
    const float* __restrict__ w,
    const int*   __restrict__ idx,
    float*       __restrict__ partial)
{
    __shared__ float4 xs4[BATCH * K4CHUNK];          // [b][kk], 16 KB

    const int rt = blockIdx.x % RTILES;
    const int ks = blockIdx.x / RTILES;

    // --- stage x chunk: 1024 float4 total, 4 per thread, coalesced ---
    {
        const float4* __restrict__ xg4 = (const float4*)x;  // [b][1024]
#pragma unroll
        for (int u = 0; u < 4; ++u) {
            const int v  = u * BLOCK + (int)threadIdx.x;    // 0..1023
            const int b  = v / K4CHUNK;
            const int kk = v % K4CHUNK;
            xs4[v] = xg4[(size_t)b * (D_MODEL / 4) + ks * K4CHUNK + kk];
        }
    }
    __syncthreads();

    const int  r      = rt * BLOCK + (int)threadIdx.x;
    const bool active = (r < REMAINED);
    const int  rc     = active ? r : (REMAINED - 1);
    const int  row    = idx[rc];

    const float4* __restrict__ wp =
        (const float4*)(w + (size_t)row * D_MODEL) + ks * K4CHUNK;

    float acc[BATCH];
#pragma unroll
    for (int b = 0; b < BATCH; ++b) acc[b] = 0.f;

    // --- K loop: 8 groups of 4 float4 (64 B/lane = full cacheline) ---
    float4 wv0 = wp[0], wv1 = wp[1], wv2 = wp[2], wv3 = wp[3];

    for (int kb = 0; kb < K4CHUNK / 4; ++kb) {
        // prefetch next group (clamped on last iter - harmless re-load)
        const int nkb = (kb < K4CHUNK / 4 - 1) ? (kb + 1) : kb;
        float4 wn0 = wp[nkb * 4 + 0];
        float4 wn1 = wp[nkb * 4 + 1];
        float4 wn2 = wp[nkb * 4 + 2];
        float4 wn3 = wp[nkb * 4 + 3];

        const float4 wreg[4] = { wv0, wv1, wv2, wv3 };
#pragma unroll
        for (int u = 0; u < 4; ++u) {
#pragma unroll
            for (int b = 0; b < BATCH; ++b) {
                // broadcast LDS read: same address on all 64 lanes
                const float4 xv = xs4[b * K4CHUNK + kb * 4 + u];
                acc[b] = fmaf(wreg[u].x, xv.x, acc[b]);
                acc[b] = fmaf(wreg[u].y, xv.y, acc[b]);
                acc[b] = fmaf(wreg[u].z, xv.z, acc[b]);
                acc[b] = fmaf(wreg[u].w, xv.w, acc[b]);
            }
        }
        wv0 = wn0; wv1 = wn1; wv2 = wn2; wv3 = wn3;
    }

    // --- store partial tile (padded rows store 0) ---
    float* p = partial + (size_t)ks * BATCH * RSLOTS + r;
    if (!active) {
#pragma unroll
        for (int b = 0; b < BATCH; ++b) acc[b] = 0.f;
    }
#pragma unroll
    for (int b = 0; b < BATCH; ++b)
        p[(size_t)b * RSLOTS] = acc[b];
}

// Phase 2: out[b][r] = sum_ks partial[ks][b][r]
#define GRID2  ((BATCH * (RSLOTS / 4)) / BLOCK)      // 144

__global__ __launch_bounds__(BLOCK) void gather_gemv_p2(
    const float* __restrict__ partial,
    float*       __restrict__ out)
{
    const int g  = blockIdx.x * BLOCK + threadIdx.x;
    const int b  = g / (RSLOTS / 4);
    const int r4 = g % (RSLOTS / 4);

    const float4* p = (const float4*)(partial) + ((size_t)b * (RSLOTS / 4) + r4);

    float4 s = make_float4(0.f, 0.f, 0.f, 0.f);
#pragma unroll
    for (int ks = 0; ks < KSPLIT; ++ks) {
        const float4 v = p[(size_t)ks * BATCH * (RSLOTS / 4)];
        s.x += v.x; s.y += v.y; s.z += v.z; s.w += v.w;
    }

    const int r0 = r4 * 4;
    float* o = out + (size_t)b * REMAINED;
    if (r0 + 3 < REMAINED) {
        o[r0 + 0] = s.x; o[r0 + 1] = s.y; o[r0 + 2] = s.z; o[r0 + 3] = s.w;
    } else {
        if (r0 + 0 < REMAINED) o[r0 + 0] = s.x;
        if (r0 + 1 < REMAINED) o[r0 + 1] = s.y;
        if (r0 + 2 < REMAINED) o[r0 + 2] = s.z;
        if (r0 + 3 < REMAINED) o[r0 + 3] = s.w;
    }
}

extern "C" void kernel_launch(void* const* d_in, const int* in_sizes, int n_in,
                              void* d_out, int out_size, void* d_ws, size_t ws_size,
                              hipStream_t stream) {
    const float* x   = (const float*)d_in[0];
    const float* w   = (const float*)d_in[1];
    const int*   idx = (const int*)d_in[2];
    float*       out = (float*)d_out;
    float*       ws  = (float*)d_ws;

    gather_gemv_p1<<<GRID1, BLOCK, 0, stream>>>(x, w, idx, ws);
    gather_gemv_p2<<<GRID2, BLOCK, 0, stream>>>(ws, out);
}